// Round 11
// baseline (193.709 us; speedup 1.0000x reference)
//
#include <hip/hip_runtime.h>
#include <math.h>

// Problem constants (GroupedKANLayer): B=2, C=31, D=7, H=W=192
#define NBATCH 2
#define NC 31
#define ND 7
#define NH 192
#define NW 192
#define HW (NH * NW)            // 36864
#define NP (NBATCH * HW)        // 73728 pixels
#define NBASIS 8
#define CLEN 56                 // ND * NBASIS
#define KP 70                   // CLEN + ND + ND

// fused tiling: 64 consecutive pixels of one image row per block
#define HPLANE 198              // 3 rows * 66 halo cols per ic

// ---------------------------------------------------------------------------
// Kernel 1: ctx = mean_d x, float4-vectorized.
// ---------------------------------------------------------------------------
__global__ __launch_bounds__(256) void ctx_mean_kernel(
    const float4* __restrict__ x4, float4* __restrict__ ctx4)
{
    const int HW4 = HW / 4;
    int idx = blockIdx.x * 256 + threadIdx.x;
    if (idx >= NBATCH * NC * HW4) return;
    int hw4 = idx % HW4;
    int bc  = idx / HW4;
    const float4* src = x4 + (size_t)bc * (ND * HW4) + hw4;
    float4 a = src[0];
#pragma unroll
    for (int d = 1; d < ND; ++d) {
        float4 v = src[d * HW4];
        a.x += v.x; a.y += v.y; a.z += v.z; a.w += v.w;
    }
    const float inv = 1.0f / 7.0f;
    a.x *= inv; a.y *= inv; a.z *= inv; a.w *= inv;
    ctx4[idx] = a;
}

// ---------------------------------------------------------------------------
// spline helper: cardinal cubic B-spline on uniform knots; cb = wlds + lane,
// coef gather at LDS stride 64 words (bank = lane%32, 2-way = free).
// ---------------------------------------------------------------------------
__device__ __forceinline__ float spline_part(float xv, const float* cb, int d)
{
    float t = (xv + 2.2f) * 2.5f;
    float fi = floorf(t);
    int i = (int)fi;
    float u = t - fi;
    float u2 = u * u, u3 = u2 * u;
    float um = 1.f - u;
    float w0 = um * um * um * (1.f / 6.f);
    float w3 = u3 * (1.f / 6.f);
    float w1 = (3.f * u3 - 6.f * u2 + 4.f) * (1.f / 6.f);
    float w2 = 1.f - w0 - w1 - w3;          // partition of unity
    int j0 = i - 3;
    float sd = 0.f;
#pragma unroll
    for (int k = 0; k < 4; ++k) {
        int j = j0 + k;
        bool valid = (j >= 0) && (j <= 7);
        int jc = valid ? j : 0;
        float wk = (k == 0) ? w0 : (k == 1) ? w1 : (k == 2) ? w2 : w3;
        float cf = cb[(d * NBASIS + jc) * 64];
        sd += (valid ? wk : 0.f) * cf;
    }
    return sd;
}

__device__ __forceinline__ float silu(float xv)
{
    return xv / (1.f + __expf(-xv));
}

// ---------------------------------------------------------------------------
// Fused conv + KAN (v2 — R4 fusion with both bugs fixed).
// Block = 256 threads / 4 waves, 64 consecutive pixels of one image row.
//
// Phase 1: stage 31-ch 3x66 ctx halo into LDS (24.5 KB), coalesced.
// Phase 2 (conv): wave wv computes oc group oc0 = {0,18,36,52}+0..17 for its
//   lane's pixel. oc0 comes from readfirstlane -> SGPR -> all weight/bias
//   reads are s_loads (bug 1 fixed); acc[18] has compile-time bounds ->
//   registers (bug 2 fixed). Groups 2/3 overlap on oc 52,53: both waves
//   compute bitwise-identical values -> duplicate LDS write is benign.
// Phase 3: acc -> wlds[oc][64] ALIASED onto the halo region (saves 18 KB,
//   LDS stays 24.5 KB -> 4+ blocks/CU).
// Phase 4 (kan): wave wv evaluates 8 channels {0-7,8-15,16-23,23-30} as
//   4 pairs (two independent spline chains per d). coef/uw/rw gathered from
//   wlds at stride 64 (2/bank = free); x loads / out stores coalesced.
// wts never touches global memory. grid = NP/64 = 1152 blocks.
// ---------------------------------------------------------------------------
__global__ __launch_bounds__(256, 4) void fused_kernel(
    const float* __restrict__ x, const float* __restrict__ ctx,
    const float* __restrict__ gw, const float* __restrict__ gb,
    float* __restrict__ out)
{
    __shared__ float lds[NC * HPLANE];   // 24552 B; reused as wlds[70*64] later

    const int tid  = threadIdx.x;
    const int lane = tid & 63;
    const int wv   = tid >> 6;                                  // wave-uniform
    const int wvu  = __builtin_amdgcn_readfirstlane(wv);        // SGPR copy

    const int p0  = blockIdx.x * 64;
    const int b   = p0 / HW;
    const int hw0 = p0 - b * HW;
    const int h   = hw0 / NW;
    const int w0  = hw0 - h * NW;        // 0, 64, or 128

    // ---- Phase 1: stage halo (threads 0..197; 31 coalesced loads each) ----
    {
        const float* cb = ctx + (b * NC) * HW;
        if (tid < HPLANE) {
            int r  = tid / 66;
            int c  = tid - r * 66;
            int gh = h + r - 1;
            int gc = w0 + c - 1;
            bool ok = (gh >= 0) && (gh < NH) && (gc >= 0) && (gc < NW);
            int off = min(max(gh, 0), NH - 1) * NW + min(max(gc, 0), NW - 1);
            float m = ok ? 1.f : 0.f;
#pragma unroll 4
            for (int ic = 0; ic < NC; ++ic)
                lds[ic * HPLANE + tid] = cb[ic * HW + off] * m;
        }
    }
    __syncthreads();

    // ---- Phase 2: conv. 18 ocs per wave, weights via SGPR s_loads ----
    const int oc0 = (wvu < 3) ? wvu * 18 : 52;      // SGPR-uniform

    float acc[18];
#pragma unroll
    for (int oc = 0; oc < 18; ++oc) acc[oc] = gb[oc0 + oc];

    const float* hb = lds + lane;
    for (int ic = 0; ic < NC; ++ic) {
        const float* t0 = hb + ic * HPLANE;
        float v00 = t0[0],   v01 = t0[1],   v02 = t0[2];
        float v10 = t0[66],  v11 = t0[67],  v12 = t0[68];
        float v20 = t0[132], v21 = t0[133], v22 = t0[134];

        const float* wb = gw + (oc0 * NC + ic) * 9;   // SGPR base -> s_loads
#pragma unroll
        for (int oc = 0; oc < 18; ++oc) {
            const float* w9 = wb + oc * (NC * 9);
            acc[oc] += v00 * w9[0] + v01 * w9[1] + v02 * w9[2]
                     + v10 * w9[3] + v11 * w9[4] + v12 * w9[5]
                     + v20 * w9[6] + v21 * w9[7] + v22 * w9[8];
        }
    }
    __syncthreads();                     // all halo reads complete

    // ---- Phase 3: exchange through LDS (aliased over halo) ----
    float* wlds = lds;                   // wlds[oc][64], 70*64*4 = 17920 B
#pragma unroll
    for (int oc = 0; oc < 18; ++oc)
        wlds[(oc0 + oc) * 64 + lane] = acc[oc];
    __syncthreads();

    // ---- Phase 4: KAN ----
    const float* cb64 = wlds + lane;

    float uw[ND], rw[ND];
#pragma unroll
    for (int d = 0; d < ND; ++d) uw[d] = cb64[(CLEN + d) * 64];
#pragma unroll
    for (int d = 0; d < ND; ++d) rw[d] = cb64[(CLEN + ND + d) * 64];

    const float* xb = x + (size_t)(b * NC) * (ND * HW) + h * NW + w0 + lane;
    float* ob = out + (b * NC) * HW + h * NW + w0 + lane;

    const int c_begin = (wv == 3) ? 23 : wv * 8;   // 8 channels per wave

#pragma unroll
    for (int i = 0; i < 4; ++i) {
        const int c0 = c_begin + 2 * i;
        const int c1 = c0 + 1;
        const float* x0 = xb + (size_t)c0 * ND * HW;
        const float* x1 = xb + (size_t)c1 * ND * HW;
        float s0 = 0.f, s1 = 0.f;
#pragma unroll
        for (int d = 0; d < ND; ++d) {
            float xv0 = x0[d * HW];
            float xv1 = x1[d * HW];
            s0 += uw[d] * spline_part(xv0, cb64, d) + rw[d] * silu(xv0);
            s1 += uw[d] * spline_part(xv1, cb64, d) + rw[d] * silu(xv1);
        }
        ob[c0 * HW] = s0;
        ob[c1 * HW] = s1;
    }
}

// ---------------------------------------------------------------------------
extern "C" void kernel_launch(void* const* d_in, const int* in_sizes, int n_in,
                              void* d_out, int out_size, void* d_ws, size_t ws_size,
                              hipStream_t stream)
{
    const float* x  = (const float*)d_in[0];   // (2,31,7,192,192)
    const float* gw = (const float*)d_in[1];   // (70,31,3,3)
    const float* gb = (const float*)d_in[2];   // (70,)
    float* out = (float*)d_out;                // (2,31,192,192)

    float* ctx = (float*)d_ws;                 // 9.1 MB scratch

    int n4 = NBATCH * NC * (HW / 4);
    ctx_mean_kernel<<<dim3((n4 + 255) / 256), 256, 0, stream>>>(
        (const float4*)x, (float4*)ctx);
    fused_kernel<<<dim3(NP / 64), 256, 0, stream>>>(x, ctx, gw, gb, out);
}

// Round 12
// 168.209 us; speedup vs baseline: 1.1516x; 1.1516x over previous
//
#include <hip/hip_runtime.h>
#include <math.h>

// Problem constants (GroupedKANLayer): B=2, C=31, D=7, H=W=192
#define NBATCH 2
#define NC 31
#define ND 7
#define NH 192
#define NW 192
#define HW (NH * NW)            // 36864
#define NP (NBATCH * HW)        // 73728 pixels
#define NBASIS 8
#define CLEN 56                 // ND * NBASIS
#define KP 70                   // CLEN + ND + ND
#define OCB 5                   // 70 = 14 * 5 -> 45 weight SGPRs/ic

// conv tiling (R6-exact, measured 51.1 us): 32x16 tile, wave-private 4-row
// strips, zero barriers, register-pipelined staging.
#define CTSX 32
#define CTSY 16
#define WROWS 4                 // tile rows per wave
#define HROWS 6                 // halo rows per wave (4 + 2)
#define HCOLS 34                // halo cols
#define WCELLS (HROWS * HCOLS)  // 204 words per wave
#define NSLOT 4                 // ceil(204/64) staging slots per lane

// kan v9 tiling: 128 px per block, px-pair per lane, 2-way channel split
#define KPX 128

// ---------------------------------------------------------------------------
// Kernel 1: ctx = mean_d x, float4-vectorized (16 B/lane).
// ---------------------------------------------------------------------------
__global__ __launch_bounds__(256) void ctx_mean_kernel(
    const float4* __restrict__ x4, float4* __restrict__ ctx4)
{
    const int HW4 = HW / 4;
    int idx = blockIdx.x * 256 + threadIdx.x;      // over NBATCH*NC*HW4
    if (idx >= NBATCH * NC * HW4) return;
    int hw4 = idx % HW4;
    int bc  = idx / HW4;
    const float4* src = x4 + (size_t)bc * (ND * HW4) + hw4;
    float4 a = src[0];
#pragma unroll
    for (int d = 1; d < ND; ++d) {
        float4 v = src[d * HW4];
        a.x += v.x; a.y += v.y; a.z += v.z; a.w += v.w;
    }
    const float inv = 1.0f / 7.0f;
    a.x *= inv; a.y *= inv; a.z *= inv; a.w *= inv;
    ctx4[idx] = a;
}

// ---------------------------------------------------------------------------
// Kernel 2 (R6-exact): 32x16 tile, 5 oc per block (blockIdx.z -> s_loads).
// Wave-private 6x34 halo strips in LDS, zero barriers, register-pipelined
// staging. Each thread: 2 pixel rows x 5 oc -> 90 FMA / 12 ds_reads per ic.
// grid = (6, 24, 14) = 2016 blocks.
// ---------------------------------------------------------------------------
__global__ __launch_bounds__(256, 4) void conv_kernel(
    const float* __restrict__ ctx, const float* __restrict__ gw,
    const float* __restrict__ gb, float* __restrict__ wts)
{
    __shared__ float tile[4][WCELLS];   // 4*204*4 = 3264 B

    const int tid  = threadIdx.x;
    const int lane = tid & 63;
    const int wv   = tid >> 6;
    const int tx0  = blockIdx.x * CTSX;
    const int by   = blockIdx.y;
    const int b    = by / (NH / CTSY);
    const int ty0  = (by - b * (NH / CTSY)) * CTSY;
    const int oc0  = blockIdx.z * OCB;            // uniform -> weights s_load
    const int wrow0 = wv * WROWS;

    int   off[NSLOT];
    float msk[NSLOT];
    bool  stv[NSLOT];
#pragma unroll
    for (int s = 0; s < NSLOT; ++s) {
        int cell = lane + s * 64;
        int r = cell / HCOLS;
        int c = cell - r * HCOLS;
        int gh = ty0 + wrow0 + r - 1;
        int gc = tx0 + c - 1;
        bool ok = (gh >= 0) && (gh < NH) && (gc >= 0) && (gc < NW);
        int ghc = min(max(gh, 0), NH - 1);
        int gcc = min(max(gc, 0), NW - 1);
        off[s] = ghc * NW + gcc;
        msk[s] = ok ? 1.f : 0.f;
        stv[s] = (cell < WCELLS);
    }

    const float* cb  = ctx + (b * NC) * HW;
    float*       myt = tile[wv];

    {   // prologue: stage ic = 0
        float t[NSLOT];
#pragma unroll
        for (int s = 0; s < NSLOT; ++s) t[s] = cb[off[s]] * msk[s];
#pragma unroll
        for (int s = 0; s < NSLOT; ++s)
            if (stv[s]) myt[lane + s * 64] = t[s];
    }

    float acc[OCB][2];
#pragma unroll
    for (int oc = 0; oc < OCB; ++oc) {
        float bv = gb[oc0 + oc];
        acc[oc][0] = bv; acc[oc][1] = bv;
    }

    const int strip = lane >> 5;        // 0/1 -> rows strip*2, strip*2+1
    const int col   = lane & 31;
    const float* t0 = myt + (strip * 2) * HCOLS + col;

    for (int ic = 0; ic < NC; ++ic) {
        float nxt[NSLOT];
        if (ic + 1 < NC) {
            const float* src = cb + (ic + 1) * HW;
#pragma unroll
            for (int s = 0; s < NSLOT; ++s) nxt[s] = src[off[s]] * msk[s];
        }

        float v[4][3];
#pragma unroll
        for (int j = 0; j < 4; ++j)
#pragma unroll
            for (int c = 0; c < 3; ++c)
                v[j][c] = t0[j * HCOLS + c];

        const float* wb = gw + (oc0 * NC + ic) * 9;
#pragma unroll
        for (int oc = 0; oc < OCB; ++oc) {
            const float* w9 = wb + oc * (NC * 9);
            float w00 = w9[0], w01 = w9[1], w02 = w9[2];
            float w10 = w9[3], w11 = w9[4], w12 = w9[5];
            float w20 = w9[6], w21 = w9[7], w22 = w9[8];
#pragma unroll
            for (int k = 0; k < 2; ++k) {
                acc[oc][k] += v[k][0] * w00 + v[k][1] * w01 + v[k][2] * w02
                            + v[k + 1][0] * w10 + v[k + 1][1] * w11 + v[k + 1][2] * w12
                            + v[k + 2][0] * w20 + v[k + 2][1] * w21 + v[k + 2][2] * w22;
            }
        }

        if (ic + 1 < NC) {
#pragma unroll
            for (int s = 0; s < NSLOT; ++s)
                if (stv[s]) myt[lane + s * 64] = nxt[s];
        }
    }

    const int pbase = b * HW + (ty0 + wrow0 + strip * 2) * NW + (tx0 + col);
#pragma unroll
    for (int oc = 0; oc < OCB; ++oc)
#pragma unroll
        for (int k = 0; k < 2; ++k)
            wts[(oc0 + oc) * NP + pbase + k * NW] = acc[oc][k];
}

// ---------------------------------------------------------------------------
// kan helpers
// ---------------------------------------------------------------------------
__device__ __forceinline__ float spline_part(float xv, const float* cb, int d)
{
    // cardinal cubic B-spline on uniform knots; cb = scoef + q*64 + lane,
    // coef at LDS word (d*8+jc)*128 + q*64 + lane -> bank = lane%32 (2-way,
    // free).
    float t = (xv + 2.2f) * 2.5f;
    float fi = floorf(t);
    int i = (int)fi;
    float u = t - fi;
    float u2 = u * u, u3 = u2 * u;
    float um = 1.f - u;
    float w0 = um * um * um * (1.f / 6.f);
    float w3 = u3 * (1.f / 6.f);
    float w1 = (3.f * u3 - 6.f * u2 + 4.f) * (1.f / 6.f);
    float w2 = 1.f - w0 - w1 - w3;          // partition of unity
    int j0 = i - 3;
    float sd = 0.f;
#pragma unroll
    for (int k = 0; k < 4; ++k) {
        int j = j0 + k;
        bool valid = (j >= 0) && (j <= 7);
        int jc = valid ? j : 0;
        float wk = (k == 0) ? w0 : (k == 1) ? w1 : (k == 2) ? w2 : w3;
        float cf = cb[(d * NBASIS + jc) * KPX];
        sd += (valid ? wk : 0.f) * cf;
    }
    return sd;
}

__device__ __forceinline__ float silu(float xv)
{
    return xv / (1.f + __expf(-xv));
}

// ---------------------------------------------------------------------------
// Kernel 3 (v9): block = 256 threads / 128 px; each lane owns a px PAIR ->
// all x loads are float2 (8 B/lane), out stores float2. Channels split
// 2-way across blockIdx.y (y=0: c0-15, y=1: c16-30); each wave takes 4
// channels as 2 pairs -> 4 independent spline chains per d. Wave 3 of y=1
// covers c27-30 (c27 duplicated by waves 2&3 -> identical value, benign).
// LDS scoef[k][q][64] (35.8 KB): staging writes and gathers both hit
// bank = lane%32 -> exactly 2/bank = free.
// grid = (576, 2) = 1152 blocks -> ~4.5 blocks/CU, 18 waves/CU.
// ---------------------------------------------------------------------------
__global__ __launch_bounds__(256, 4) void kan_kernel(
    const float* __restrict__ x, const float* __restrict__ wts,
    float* __restrict__ out)
{
    __shared__ float scoef[KP * KPX];   // 70*128*4 = 35840 B
    const int tid = threadIdx.x;
    const int p0  = blockIdx.x * KPX;

    // stage: thread handles (k, g): float2 of px (2g, 2g+1) -> q-split LDS
    for (int f = tid; f < KP * 64; f += 256) {
        int k = f >> 6;
        int g = f & 63;
        float2 v = *(const float2*)(wts + (size_t)k * NP + p0 + g * 2);
        scoef[k * KPX + g]      = v.x;   // q = 0
        scoef[k * KPX + 64 + g] = v.y;   // q = 1
    }
    __syncthreads();

    const int lane = tid & 63;
    const int wv   = tid >> 6;
    const int b    = p0 / HW;             // uniform (HW % 128 == 0)
    const int hw   = (p0 - b * HW) + lane * 2;

    const float* cb0 = scoef + lane;       // q = 0
    const float* cb1 = scoef + 64 + lane;  // q = 1

    // uw/rw for both pixels of the pair
    float uw0[ND], uw1[ND], rw0[ND], rw1[ND];
#pragma unroll
    for (int d = 0; d < ND; ++d) {
        uw0[d] = cb0[(CLEN + d) * KPX];
        uw1[d] = cb1[(CLEN + d) * KPX];
        rw0[d] = cb0[(CLEN + ND + d) * KPX];
        rw1[d] = cb1[(CLEN + ND + d) * KPX];
    }

    const int cy = blockIdx.y;
    const int c_begin = (cy == 0) ? wv * 4
                                  : ((wv == 3) ? 27 : 16 + wv * 4);

    const float* xb = x + (size_t)(b * NC) * (ND * HW) + hw;
    float* ob = out + (b * NC) * HW + hw;

#pragma unroll
    for (int i = 0; i < 2; ++i) {
        const int c0 = c_begin + 2 * i;
        const int c1 = c0 + 1;
        const float* x0 = xb + (size_t)c0 * ND * HW;
        const float* x1 = xb + (size_t)c1 * ND * HW;
        float s0x = 0.f, s0y = 0.f, s1x = 0.f, s1y = 0.f;
#pragma unroll
        for (int d = 0; d < ND; ++d) {
            float2 xv0 = *(const float2*)(x0 + d * HW);
            float2 xv1 = *(const float2*)(x1 + d * HW);
            s0x += uw0[d] * spline_part(xv0.x, cb0, d) + rw0[d] * silu(xv0.x);
            s0y += uw1[d] * spline_part(xv0.y, cb1, d) + rw1[d] * silu(xv0.y);
            s1x += uw0[d] * spline_part(xv1.x, cb0, d) + rw0[d] * silu(xv1.x);
            s1y += uw1[d] * spline_part(xv1.y, cb1, d) + rw1[d] * silu(xv1.y);
        }
        float2 o0; o0.x = s0x; o0.y = s0y;
        float2 o1; o1.x = s1x; o1.y = s1y;
        *(float2*)(ob + (size_t)c0 * HW) = o0;
        *(float2*)(ob + (size_t)c1 * HW) = o1;
    }
}

// ---------------------------------------------------------------------------
extern "C" void kernel_launch(void* const* d_in, const int* in_sizes, int n_in,
                              void* d_out, int out_size, void* d_ws, size_t ws_size,
                              hipStream_t stream)
{
    const float* x  = (const float*)d_in[0];   // (2,31,7,192,192)
    const float* gw = (const float*)d_in[1];   // (70,31,3,3)
    const float* gb = (const float*)d_in[2];   // (70,)
    float* out = (float*)d_out;                // (2,31,192,192)

    float* ctx = (float*)d_ws;                       // 9.1 MB
    float* wts = ctx + (size_t)NBATCH * NC * HW;     // 20.6 MB

    int n4 = NBATCH * NC * (HW / 4);
    ctx_mean_kernel<<<dim3((n4 + 255) / 256), 256, 0, stream>>>(
        (const float4*)x, (float4*)ctx);
    conv_kernel<<<dim3(NW / CTSX, (NH / CTSY) * NBATCH, KP / OCB), 256, 0, stream>>>(ctx, gw, gb, wts);
    kan_kernel<<<dim3(NP / KPX, 2), 256, 0, stream>>>(x, wts, out);
}